// Round 1
// 576.875 us; speedup vs baseline: 1.3144x; 1.3144x over previous
//
#include <hip/hip_runtime.h>

#define CDIM 128

typedef short short8 __attribute__((ext_vector_type(8)));
typedef float f32x4 __attribute__((ext_vector_type(4)));

// ---- fp32 -> bf16 split helpers (RNE) --------------------------------------
__device__ __forceinline__ unsigned short f2bf(float f) {
  unsigned int u = __builtin_bit_cast(unsigned int, f);
  u += 0x7fffu + ((u >> 16) & 1u);
  return (unsigned short)(u >> 16);
}
__device__ __forceinline__ float bf2f(unsigned short b) {
  return __builtin_bit_cast(float, (unsigned int)b << 16);
}
__device__ __forceinline__ void split_bf(float v, unsigned short& h,
                                         unsigned short& l) {
  h = f2bf(v);
  l = f2bf(v - bf2f(h));
}

// d_ws layout:
//   [0, 262144) bytes: W fragments, 4 matrices (Wk,Wv,Wr,Wo) x 32768 ushorts:
//     matrix m: hi frags at wf + m*32768, lo frags at wf + m*32768 + 16384
//     frag elem index: ((kt*8 + nt)*64 + lane)*8 + e
//     value = W[j=nt*16+(lane&15)][c=kt*32+(lane>>4)*8+e]   (B = W^T)
//   [262144, +3*N*C*4): K, V, R fp32 node buffers

// ---- pack weights into MFMA B-fragment order (runs once, 16384 threads) ----
__global__ __launch_bounds__(256) void pack_w(
    const float* __restrict__ Wk, const float* __restrict__ Wv,
    const float* __restrict__ Wr, const float* __restrict__ Wo,
    unsigned short* __restrict__ wf) {
  const int f = blockIdx.x * 256 + threadIdx.x;  // 0..16383
  const int m = f >> 12;
  const int idx = (f & 4095) * 4;                // 0..16380, step 4
  const int e0 = idx & 7;                        // 0 or 4
  const int l = (idx >> 3) & 63;
  const int nt = (idx >> 9) & 7;
  const int kt = idx >> 12;
  const float* W = (m == 0) ? Wk : (m == 1) ? Wv : (m == 2) ? Wr : Wo;
  const int j = nt * 16 + (l & 15);
  const int c = kt * 32 + (l >> 4) * 8 + e0;
  float4 v = *(const float4*)(W + j * CDIM + c);
  ushort4 h, lo;
  split_bf(v.x, h.x, lo.x);
  split_bf(v.y, h.y, lo.y);
  split_bf(v.z, h.z, lo.z);
  split_bf(v.w, h.w, lo.w);
  unsigned short* base = wf + m * 32768;
  *(ushort4*)(base + idx) = h;
  *(ushort4*)(base + 16384 + idx) = lo;
}

// ---- MFMA core: 128 rows/block, 256 thr (4 waves x 32 rows), W in LDS ------
// A-frag (lane view): row = lane&15 (+16*mt), k = (lane>>4)*8 + e (+32*kt).
// Split-bf16: acc += Ahi*Bhi + Alo*Bhi + Ahi*Blo  (fp32-accurate).
// D layout: col = lane&15, row = (lane>>4)*4 + reg.

#define MFMA __builtin_amdgcn_mfma_f32_16x16x32_bf16

__device__ __forceinline__ void stage_w(unsigned short* Wl,
                                        const unsigned short* wsrc, int t) {
  const float4* src = (const float4*)wsrc;
  float4* dst = (float4*)Wl;
#pragma unroll
  for (int it = 0; it < 16; ++it) dst[it * 256 + t] = src[it * 256 + t];
}

__device__ __forceinline__ void mfma_all(const unsigned short* Wl,
                                         const short8 ahi[2][4],
                                         const short8 alo[2][4],
                                         f32x4 acc[2][8], int lane) {
#pragma unroll
  for (int kt = 0; kt < 4; ++kt) {
#pragma unroll
    for (int nt = 0; nt < 8; ++nt) {
      const int fo = ((kt * 8 + nt) * 64 + lane) * 8;
      short8 bhi = *(const short8*)(Wl + fo);
      short8 blo = *(const short8*)(Wl + 16384 + fo);
      acc[0][nt] = MFMA(ahi[0][kt], bhi, acc[0][nt], 0, 0, 0);
      acc[1][nt] = MFMA(ahi[1][kt], bhi, acc[1][nt], 0, 0, 0);
      acc[0][nt] = MFMA(alo[0][kt], bhi, acc[0][nt], 0, 0, 0);
      acc[1][nt] = MFMA(alo[1][kt], bhi, acc[1][nt], 0, 0, 0);
      acc[0][nt] = MFMA(ahi[0][kt], blo, acc[0][nt], 0, 0, 0);
      acc[1][nt] = MFMA(ahi[1][kt], blo, acc[1][nt], 0, 0, 0);
    }
  }
}

// ---------------- Kernel A: node stage  K/V/R = mix(x,px) @ W^T -------------
__global__ __launch_bounds__(256, 2) void node_mfma(
    const float* __restrict__ x, const float* __restrict__ px,
    const float* __restrict__ tmk, const float* __restrict__ tmv,
    const float* __restrict__ tmr, const unsigned short* __restrict__ wf,
    float* __restrict__ kvr, int N) {
  __shared__ alignas(16) unsigned short Wl[32768];  // 64 KB
  const int t = threadIdx.x;
  const int m = blockIdx.y;
  stage_w(Wl, wf + m * 32768, t);
  const float* __restrict__ tm = (m == 0) ? tmk : (m == 1) ? tmv : tmr;
  const int lane = t & 63;
  const int w = t >> 6;
  const int lr = lane & 15, lg = lane >> 4;
  const int rbase = blockIdx.x * 128 + w * 32;

  short8 ahi[2][4], alo[2][4];
#pragma unroll
  for (int kt = 0; kt < 4; ++kt) {
    const int c0 = kt * 32 + lg * 8;
    float tmx[8];
    *(float4*)tmx = *(const float4*)(tm + c0);
    *(float4*)(tmx + 4) = *(const float4*)(tm + c0 + 4);
#pragma unroll
    for (int mt = 0; mt < 2; ++mt) {
      const int r = rbase + mt * 16 + lr;
      float xa[8], pa[8];
      if (r < N) {
        const float* xp = x + (size_t)r * CDIM + c0;
        const float* pp = px + (size_t)r * CDIM + c0;
        *(float4*)xa = *(const float4*)xp;
        *(float4*)(xa + 4) = *(const float4*)(xp + 4);
        *(float4*)pa = *(const float4*)pp;
        *(float4*)(pa + 4) = *(const float4*)(pp + 4);
      } else {
#pragma unroll
        for (int q = 0; q < 8; ++q) { xa[q] = 0.f; pa[q] = 0.f; }
      }
      short8 hv, lv;
#pragma unroll
      for (int q = 0; q < 8; ++q) {
        float xm = pa[q] + tmx[q] * (xa[q] - pa[q]);
        unsigned short hb, lb;
        split_bf(xm, hb, lb);
        hv[q] = (short)hb;
        lv[q] = (short)lb;
      }
      ahi[mt][kt] = hv;
      alo[mt][kt] = lv;
    }
  }
  __syncthreads();

  f32x4 acc[2][8];
#pragma unroll
  for (int mt = 0; mt < 2; ++mt)
#pragma unroll
    for (int nt = 0; nt < 8; ++nt) {
      f32x4 z = {0.f, 0.f, 0.f, 0.f};
      acc[mt][nt] = z;
    }
  mfma_all(Wl, ahi, alo, acc, lane);

  float* outb = kvr + (size_t)m * N * CDIM;
#pragma unroll
  for (int mt = 0; mt < 2; ++mt) {
    const int rb = rbase + mt * 16 + lg * 4;
#pragma unroll
    for (int nt = 0; nt < 8; ++nt) {
#pragma unroll
      for (int g = 0; g < 4; ++g) {
        const int r = rb + g;
        if (r < N) outb[(size_t)r * CDIM + nt * 16 + lr] = acc[mt][nt][g];
      }
    }
  }
}

// ---------------- Kernel B: edge stage  out = (r*wkv) @ Wo^T ----------------
__global__ __launch_bounds__(256, 2) void edge_mfma(
    const float* __restrict__ ah, const float* __restrict__ bh,
    const int* __restrict__ sidx, const int* __restrict__ tidx,
    const int* __restrict__ ip, const int* __restrict__ Tp,
    const float* __restrict__ time_w, const unsigned short* __restrict__ wf,
    const float* __restrict__ kvr, float* __restrict__ out, int N) {
  __shared__ alignas(16) unsigned short Wl[32768];  // 64 KB
  const int t = threadIdx.x;
  stage_w(Wl, wf + 3 * 32768, t);  // Wo
  const int lane = t & 63;
  const int w = t >> 6;
  const int lr = lane & 15, lg = lane >> 4;
  const size_t rbase = (size_t)blockIdx.x * 128 + w * 32;
  const float* __restrict__ Kb = kvr;
  const float* __restrict__ Vb = kvr + (size_t)N * CDIM;
  const float* __restrict__ Rb = kvr + 2 * (size_t)N * CDIM;
  const float dec = -(float)(Tp[0] - ip[0] - 1);

  const size_t er0 = rbase + lr, er1 = rbase + 16 + lr;
  const int s0 = sidx[er0], t0 = tidx[er0];
  const int s1 = sidx[er1], t1 = tidx[er1];

  short8 ahi[2][4], alo[2][4];
#pragma unroll
  for (int kt = 0; kt < 4; ++kt) {
    const int c0 = kt * 32 + lg * 8;
    float tww[8], wd[8];
    *(float4*)tww = *(const float4*)(time_w + c0);
    *(float4*)(tww + 4) = *(const float4*)(time_w + c0 + 4);
#pragma unroll
    for (int q = 0; q < 8; ++q) wd[q] = __expf(dec * tww[q]);
#pragma unroll
    for (int mt = 0; mt < 2; ++mt) {
      const size_t r = mt ? er1 : er0;
      const int se = mt ? s1 : s0;
      const int te = mt ? t1 : t0;
      float aa[8], bb[8], kk[8], vv[8], rr[8];
      {
        const float* p = ah + r * CDIM + c0;
        *(float4*)aa = *(const float4*)p;
        *(float4*)(aa + 4) = *(const float4*)(p + 4);
      }
      {
        const float* p = bh + r * CDIM + c0;
        *(float4*)bb = *(const float4*)p;
        *(float4*)(bb + 4) = *(const float4*)(p + 4);
      }
      {
        const float* p = Kb + (size_t)se * CDIM + c0;
        *(float4*)kk = *(const float4*)p;
        *(float4*)(kk + 4) = *(const float4*)(p + 4);
      }
      {
        const float* p = Vb + (size_t)te * CDIM + c0;
        *(float4*)vv = *(const float4*)p;
        *(float4*)(vv + 4) = *(const float4*)(p + 4);
      }
      {
        const float* p = Rb + (size_t)se * CDIM + c0;
        *(float4*)rr = *(const float4*)p;
        *(float4*)(rr + 4) = *(const float4*)(p + 4);
      }
      short8 hv, lv;
#pragma unroll
      for (int q = 0; q < 8; ++q) {
        float ke = __expf(fminf(kk[q], 60.0f));
        float sr = __builtin_amdgcn_rcpf(1.0f + __expf(-rr[q]));
        float p = sr * (aa[q] + wd[q] * ke * vv[q]) *
                  __builtin_amdgcn_rcpf(bb[q] + ke + 1e-20f);
        unsigned short hb, lb;
        split_bf(p, hb, lb);
        hv[q] = (short)hb;
        lv[q] = (short)lb;
      }
      ahi[mt][kt] = hv;
      alo[mt][kt] = lv;
    }
  }
  __syncthreads();

  f32x4 acc[2][8];
#pragma unroll
  for (int mt = 0; mt < 2; ++mt)
#pragma unroll
    for (int nt = 0; nt < 8; ++nt) {
      f32x4 z = {0.f, 0.f, 0.f, 0.f};
      acc[mt][nt] = z;
    }
  mfma_all(Wl, ahi, alo, acc, lane);

#pragma unroll
  for (int mt = 0; mt < 2; ++mt) {
    const size_t rb = rbase + mt * 16 + lg * 4;
#pragma unroll
    for (int nt = 0; nt < 8; ++nt) {
      float* o = out + rb * CDIM + nt * 16 + lr;
#pragma unroll
      for (int g = 0; g < 4; ++g) o[(size_t)g * CDIM] = acc[mt][nt][g];
    }
  }
}

extern "C" void kernel_launch(void* const* d_in, const int* in_sizes, int n_in,
                              void* d_out, int out_size, void* d_ws,
                              size_t ws_size, hipStream_t stream) {
  const float* x   = (const float*)d_in[0];
  const float* px  = (const float*)d_in[1];
  const float* ah  = (const float*)d_in[2];
  const float* bh  = (const float*)d_in[3];
  const float* Wk  = (const float*)d_in[4];
  const float* Wv  = (const float*)d_in[5];
  const float* Wr  = (const float*)d_in[6];
  const float* Wo  = (const float*)d_in[7];
  const float* tmk = (const float*)d_in[8];
  const float* tmv = (const float*)d_in[9];
  const float* tmr = (const float*)d_in[10];
  const float* tw  = (const float*)d_in[11];
  const int* sidx  = (const int*)d_in[12];
  const int* tidx  = (const int*)d_in[13];
  const int* ip    = (const int*)d_in[14];
  const int* Tp    = (const int*)d_in[15];
  const int N = in_sizes[0] / CDIM;   // 25000
  const int E = in_sizes[2] / CDIM;   // 400000

  unsigned short* wf = (unsigned short*)d_ws;   // 4 x 32768 ushorts = 256 KB
  float* kvr = (float*)(wf + 4 * 32768);        // 3 * N * C floats
  float* out = (float*)d_out;

  pack_w<<<dim3(64), dim3(256), 0, stream>>>(Wk, Wv, Wr, Wo, wf);
  node_mfma<<<dim3((N + 127) / 128, 3), dim3(256), 0, stream>>>(
      x, px, tmk, tmv, tmr, wf, kvr, N);
  edge_mfma<<<dim3(E / 128), dim3(256), 0, stream>>>(
      ah, bh, sidx, tidx, ip, Tp, tw, wf, kvr, out, N);
}